// Round 2
// baseline (2176.242 us; speedup 1.0000x reference)
//
#include <hip/hip_runtime.h>
#include <cstdint>
#include <cstddef>

// ---------------- problem constants ----------------
#define N_B        256
#define F_DIM      64
#define H_DIM      512
#define OUT_DIM    65
#define N_LEAF     512
#define N_INT      511
#define N_NODE     1023
#define IIN_PAD    224   // 194 padded to multiple of 32
#define TREE_STRIDE 66   // 65 padded

#define MODE_ACT  0
#define MODE_TREE 1
#define MODE_ROOT 2

typedef _Float16 f16;
typedef _Float16 f16x8  __attribute__((ext_vector_type(8)));
typedef _Float16 f16x4v __attribute__((ext_vector_type(4)));
typedef float    f32x4  __attribute__((ext_vector_type(4)));

using gas_t = const __attribute__((address_space(1))) void*;
using las_t = __attribute__((address_space(3))) void*;

// async global->LDS, 16B per lane. LDS dest is wave-uniform base + lane*16;
// the GLOBAL address is per-lane, which is what carries our layout permutation.
__device__ __forceinline__ void gload_lds16(const void* g, void* l) {
  gas_t gp = (gas_t)(uintptr_t)g;
  las_t lp = (las_t)(uint32_t)(uintptr_t)l;  // low 32 bits of generic LDS ptr = LDS offset
  __builtin_amdgcn_global_load_lds(gp, lp, 16, 0, 0);
}

// ---------------- GEMM: C[M x Npad] = A[M x K] * Wt[Npad x K]^T + bias ----------------
// A row-major (lda=K, K multiple of 32, M multiple of 128).
// Wt is the weight pre-transposed to [n][k] row-major, Npad multiple of 128.
//
// LDS tile layout (conflict-free): [rowgroup16][kseg4][row16] in 16B segments.
//   segment s = rg*64 + q*16 + i  holds  T[row = rg*16+i][k = q*8 .. q*8+7]
// Fragment read for rowgroup rg is then exactly  base + rg*1024B + lane*16B
// -> lane-contiguous -> zero bank conflicts (vs 8-way with [row][k] layout).
__global__ __launch_bounds__(256) void gemm_f16_k(
    const f16* __restrict__ A, int K,
    const f16* __restrict__ Wt,
    const float* __restrict__ bias, int realN, int nCB,
    int relu, int mode,
    f16* __restrict__ outAct,          // MODE_ACT: [M x 512] fp16
    f16* __restrict__ tree,            // MODE_TREE
    int lvl, int nodeBase, int rowOffset,
    float* __restrict__ dOut)          // MODE_ROOT
{
  __shared__ f16 lA[128 * 32];
  __shared__ f16 lB[128 * 32];

  const int tid  = threadIdx.x;
  const int bid  = blockIdx.x;
  const int cb   = bid % nCB;
  const int rb   = bid / nCB;
  const long rowBase = (long)rb * 128;
  const int colBase  = cb * 128;
  const int lane = tid & 63;
  const int quad = lane >> 4;
  const int l16  = lane & 15;
  const int wave = tid >> 6;
  const int wm   = (wave & 1) * 64;
  const int wn   = (wave >> 1) * 64;

  // staging: 512 16B segments per tile; thread t does segments t and t+256.
  // segment s -> global (row = (s>>6)*16 + (s&15), kseg = (s>>4)&3)
  const int segA = tid;
  const int segB = tid + 256;
  const int rA0 = ((segA >> 6) << 4) + (segA & 15), kA0 = ((segA >> 4) & 3) * 8;
  const int rA1 = ((segB >> 6) << 4) + (segB & 15), kA1 = ((segB >> 4) & 3) * 8;

  const f16* Ab = A  + rowBase * (long)K;
  const f16* Bb = Wt + (long)colBase * K;
  const f16* gA0 = Ab + (long)rA0 * K + kA0;
  const f16* gA1 = Ab + (long)rA1 * K + kA1;
  const f16* gB0 = Bb + (long)rA0 * K + kA0;
  const f16* gB1 = Bb + (long)rA1 * K + kA1;

  f32x4 acc[4][4];
  const f32x4 z = {0.f, 0.f, 0.f, 0.f};
#pragma unroll
  for (int i = 0; i < 4; i++)
#pragma unroll
    for (int j = 0; j < 4; j++) acc[i][j] = z;

  const int rgm = wm >> 4;   // A rowgroup base (in units of 16 rows)
  const int rgn = wn >> 4;   // B rowgroup base

  for (int k0 = 0; k0 < K; k0 += 32) {
    gload_lds16(gA0 + k0, &lA[segA * 8]);
    gload_lds16(gA1 + k0, &lA[segB * 8]);
    gload_lds16(gB0 + k0, &lB[segA * 8]);
    gload_lds16(gB1 + k0, &lB[segB * 8]);
    __syncthreads();

    f16x8 af[4], bf[4];
#pragma unroll
    for (int mt = 0; mt < 4; mt++)
      af[mt] = *(const f16x8*)&lA[(rgm + mt) * 512 + lane * 8];
#pragma unroll
    for (int nt = 0; nt < 4; nt++)
      bf[nt] = *(const f16x8*)&lB[(rgn + nt) * 512 + lane * 8];

#pragma unroll
    for (int mt = 0; mt < 4; mt++)
#pragma unroll
      for (int nt = 0; nt < 4; nt++)
        acc[mt][nt] = __builtin_amdgcn_mfma_f32_16x16x32_f16(af[mt], bf[nt], acc[mt][nt], 0, 0, 0);
    __syncthreads();
  }

  // epilogue: C/D layout col=lane&15, row=quad*4+reg (m89-verified)
#pragma unroll
  for (int mt = 0; mt < 4; mt++) {
#pragma unroll
    for (int nt = 0; nt < 4; nt++) {
#pragma unroll
      for (int r = 0; r < 4; r++) {
        const int  mloc = wm + mt * 16 + quad * 4 + r;
        const int  nloc = wn + nt * 16 + l16;
        const long grow = rowBase + mloc;
        const int  gcol = colBase + nloc;
        float v = acc[mt][nt][r];
        if (gcol < realN) v += bias[gcol];
        if (relu) v = v > 0.f ? v : 0.f;
        if (mode == MODE_ACT) {
          outAct[grow * 512 + gcol] = (f16)v;
        } else if (mode == MODE_TREE) {
          if (gcol < OUT_DIM) {
            const long gr   = (long)rowOffset + grow;
            const long bb   = gr >> lvl;
            const long ii   = gr & ((1L << lvl) - 1);
            const long node = nodeBase + ii;
            tree[(bb * N_NODE + node) * TREE_STRIDE + gcol] = (f16)v;
          }
        } else { // MODE_ROOT
          if (gcol == 0) dOut[(long)rowOffset + grow] = v;
        }
      }
    }
  }
}

// ---------------- weight transpose + cast: Wt[n*Kpad + k] = W[k*N + n] ----------------
__global__ void wcast(const float* __restrict__ W, f16* __restrict__ Wt,
                      int K, int N, int Kpad, int Npad) {
  int idx = blockIdx.x * 256 + threadIdx.x;
  if (idx >= Npad * Kpad) return;
  int n = idx / Kpad;
  int k = idx - n * Kpad;
  float v = (n < N && k < K) ? W[(long)k * N + n] : 0.f;
  Wt[idx] = (f16)v;
}

// ---------------- fp32 -> fp16 contiguous cast (4 elems/thread) ----------------
__global__ void cast_chunk(const float* __restrict__ src, f16* __restrict__ dst, long n) {
  long i = ((long)blockIdx.x * 256 + threadIdx.x) * 4;
  if (i >= n) return;
  float4 v = *(const float4*)(src + i);
  f16x4v o = {(f16)v.x, (f16)v.y, (f16)v.z, (f16)v.w};
  *(f16x4v*)(dst + i) = o;
}

// ---------------- gather internal-node inputs: X[r][0:224] = [feat(64)|L(65)|R(65)|0pad] ----------------
__global__ void gather_int(const float* __restrict__ feats, const f16* __restrict__ tree,
                           f16* __restrict__ X, int lvl, int nodeBase, int rowOffset) {
  int c = threadIdx.x;
  if (c >= IIN_PAD) return;
  long r = (long)rowOffset + blockIdx.x;
  int b = (int)(r >> lvl);
  int i = (int)(r & ((1 << lvl) - 1));
  int node = nodeBase + i;
  float v = 0.f;
  if (c < F_DIM) {
    v = feats[((long)b * N_INT + node) * F_DIM + c];
  } else if (c < F_DIM + OUT_DIM) {
    v = (float)tree[((long)b * N_NODE + (2 * node + 1)) * TREE_STRIDE + (c - F_DIM)];
  } else if (c < F_DIM + 2 * OUT_DIM) {
    v = (float)tree[((long)b * N_NODE + (2 * node + 2)) * TREE_STRIDE + (c - F_DIM - OUT_DIM)];
  }
  X[(long)blockIdx.x * IIN_PAD + c] = (f16)v;
}

// ---------------- host orchestration ----------------
extern "C" void kernel_launch(void* const* d_in, const int* in_sizes, int n_in,
                              void* d_out, int out_size, void* d_ws, size_t ws_size,
                              hipStream_t stream) {
  const float* leaf_feats     = (const float*)d_in[0];
  const float* internal_feats = (const float*)d_in[1];
  const float* lw0 = (const float*)d_in[2];
  const float* lb0 = (const float*)d_in[3];
  const float* lw1 = (const float*)d_in[4];
  const float* lb1 = (const float*)d_in[5];
  const float* lw2 = (const float*)d_in[6];
  const float* lb2 = (const float*)d_in[7];
  const float* lwo = (const float*)d_in[8];
  const float* lbo = (const float*)d_in[9];
  const float* iw0 = (const float*)d_in[10];
  const float* ib0 = (const float*)d_in[11];
  const float* iw1 = (const float*)d_in[12];
  const float* ib1 = (const float*)d_in[13];
  const float* iw2 = (const float*)d_in[14];
  const float* ib2 = (const float*)d_in[15];
  const float* iwo = (const float*)d_in[16];
  const float* ibo = (const float*)d_in[17];
  float* dOut = (float*)d_out;

  char* ws = (char*)d_ws;
  size_t off = 0;
  auto alloc = [&](size_t bytes) -> void* {
    void* p = ws + off;
    off += (bytes + 255) & ~(size_t)255;
    return p;
  };

  // fixed regions (~37 MB)
  f16* lw0t = (f16*)alloc((size_t)512 * 64 * 2);
  f16* lw1t = (f16*)alloc((size_t)512 * 512 * 2);
  f16* lw2t = (f16*)alloc((size_t)512 * 512 * 2);
  f16* lwot = (f16*)alloc((size_t)128 * 512 * 2);
  f16* iw0t = (f16*)alloc((size_t)512 * IIN_PAD * 2);
  f16* iw1t = (f16*)alloc((size_t)512 * 512 * 2);
  f16* iw2t = (f16*)alloc((size_t)512 * 512 * 2);
  f16* iwot = (f16*)alloc((size_t)128 * 512 * 2);
  f16* tree = (f16*)alloc((size_t)N_B * N_NODE * TREE_STRIDE * 2);

  // chunked activation regions sized from remaining workspace
  const size_t perRow = (size_t)(F_DIM + IIN_PAD + 512 + 512) * 2;  // 2624 B/row
  long chunk = 0;
  if (ws_size > off + 1024) chunk = (long)((ws_size - off - 1024) / perRow);
  chunk &= ~127L;
  if (chunk > 131072) chunk = 131072;
  if (chunk < 128)    chunk = 128;
  f16* Xleaf = (f16*)alloc((size_t)chunk * F_DIM * 2);
  f16* Xint  = (f16*)alloc((size_t)chunk * IIN_PAD * 2);
  f16* actA  = (f16*)alloc((size_t)chunk * 512 * 2);
  f16* actB  = (f16*)alloc((size_t)chunk * 512 * 2);

  auto wc = [&](const float* W, f16* Wt, int K, int N, int Kpad, int Npad) {
    int total = Npad * Kpad;
    wcast<<<dim3((total + 255) / 256), dim3(256), 0, stream>>>(W, Wt, K, N, Kpad, Npad);
  };
  auto gemm = [&](const f16* Aa, int K, const f16* Wt, const float* bias, int realN,
                  int Npad, long M, int relu, int mode, f16* outAct,
                  int lvl, int nodeBase, long rowOff) {
    int nCB = Npad / 128;
    gemm_f16_k<<<dim3((unsigned)((M / 128) * nCB)), dim3(256), 0, stream>>>(
        Aa, K, Wt, bias, realN, nCB, relu, mode, outAct, tree, lvl, nodeBase, (int)rowOff, dOut);
  };

  // weights: cast + transpose (+pad K to x32, N to x128)
  wc(lw0, lw0t, 64, 512, 64, 512);
  wc(lw1, lw1t, 512, 512, 512, 512);
  wc(lw2, lw2t, 512, 512, 512, 512);
  wc(lwo, lwot, 512, 65, 512, 128);
  wc(iw0, iw0t, 194, 512, IIN_PAD, 512);
  wc(iw1, iw1t, 512, 512, 512, 512);
  wc(iw2, iw2t, 512, 512, 512, 512);
  wc(iwo, iwot, 512, 65, 512, 128);

  // ---- leaf MLP: nodes 511..1022 ----
  const long Mleaf = (long)N_B * N_LEAF;  // 131072
  for (long c0 = 0; c0 < Mleaf; c0 += chunk) {
    long cm = (Mleaf - c0 < chunk) ? (Mleaf - c0) : chunk;
    long n = cm * F_DIM;
    cast_chunk<<<dim3((unsigned)(n / 1024)), dim3(256), 0, stream>>>(leaf_feats + c0 * F_DIM, Xleaf, n);
    gemm(Xleaf, 64,  lw0t, lb0, 512, 512, cm, 1, MODE_ACT, actA, 0, 0, 0);
    gemm(actA, 512,  lw1t, lb1, 512, 512, cm, 1, MODE_ACT, actB, 0, 0, 0);
    gemm(actB, 512,  lw2t, lb2, 512, 512, cm, 1, MODE_ACT, actA, 0, 0, 0);
    gemm(actA, 512,  lwot, lbo, 65,  128, cm, 0, MODE_TREE, nullptr, 9, N_INT, c0);
  }

  // ---- internal levels, bottom-up ----
  for (int l = 8; l >= 0; l--) {
    long R = (long)N_B << l;
    int s = (1 << l) - 1;
    for (long c0 = 0; c0 < R; c0 += chunk) {
      long cm = (R - c0 < chunk) ? (R - c0) : chunk;
      gather_int<<<dim3((unsigned)cm), dim3(256), 0, stream>>>(internal_feats, tree, Xint, l, s, (int)c0);
      gemm(Xint, IIN_PAD, iw0t, ib0, 512, 512, cm, 1, MODE_ACT, actA, 0, 0, 0);
      gemm(actA, 512,     iw1t, ib1, 512, 512, cm, 1, MODE_ACT, actB, 0, 0, 0);
      gemm(actB, 512,     iw2t, ib2, 512, 512, cm, 1, MODE_ACT, actA, 0, 0, 0);
      gemm(actA, 512,     iwot, ibo, 65,  128, cm, 0, (l == 0) ? MODE_ROOT : MODE_TREE, nullptr, l, s, c0);
    }
  }
  (void)in_sizes; (void)n_in; (void)out_size;
}

// Round 3
// 1461.154 us; speedup vs baseline: 1.4894x; 1.4894x over previous
//
#include <hip/hip_runtime.h>
#include <cstdint>
#include <cstddef>

// ---------------- problem constants ----------------
#define N_B        256
#define F_DIM      64
#define H_DIM      512
#define OUT_DIM    65
#define N_LEAF     512
#define N_INT      511
#define N_NODE     1023
#define IIN_PAD    224   // 194 padded to multiple of 32
#define TREE_STRIDE 66   // 65 padded

#define MODE_ACT  0
#define MODE_TREE 1
#define MODE_ROOT 2

typedef _Float16 f16;
typedef _Float16 f16x8  __attribute__((ext_vector_type(8)));
typedef _Float16 f16x4v __attribute__((ext_vector_type(4)));
typedef float    f32x4  __attribute__((ext_vector_type(4)));

using gas_t = const __attribute__((address_space(1))) void*;
using las_t = __attribute__((address_space(3))) void*;

// async global->LDS, 16B per lane. LDS dest is wave-uniform base + lane*16;
// the GLOBAL address carries any layout permutation.
__device__ __forceinline__ void gload_lds16(const void* g, void* l) {
  gas_t gp = (gas_t)(uintptr_t)g;
  las_t lp = (las_t)(uint32_t)(uintptr_t)l;
  __builtin_amdgcn_global_load_lds(gp, lp, 16, 0, 0);
}

// ---------------- GEMM: C[M x Npad] = A[M x K] * Wt[Npad x K]^T + bias ----------------
// LDS layout (XOR-swizzled): segment s (16B) holds T[row=s>>2][kseg=(s^(s>>2))&3].
//  - staging: thread t stages segment t: row=t>>2, so 4 consecutive lanes read the
//    SAME 64-B global line (permuted within-line) -> coalesced like round 1.
//  - fragment read: addr = row*64 + (quad^(row&3))*16 B -> 8-lane groups hit
//    4 bank-groups x 2 lanes = 2-way = free (m136).
__global__ __launch_bounds__(256) void gemm_f16_k(
    const f16* __restrict__ A, int K,
    const f16* __restrict__ Wt,
    const float* __restrict__ bias, int realN, int nCB,
    int relu, int mode,
    f16* __restrict__ outAct,          // MODE_ACT: [M x 512] fp16
    f16* __restrict__ tree,            // MODE_TREE
    int lvl, int nodeBase, int rowOffset,
    float* __restrict__ dOut)          // MODE_ROOT
{
  __shared__ f16 sbuf[128 * 32 * 2];   // lA: [0,4096) f16, lB: [4096,8192) f16
  f16* lA = sbuf;
  f16* lB = sbuf + 4096;

  const int tid  = threadIdx.x;
  const int bid  = blockIdx.x;
  const int cb   = bid % nCB;
  const int rb   = bid / nCB;
  const long rowBase = (long)rb * 128;
  const int colBase  = cb * 128;
  const int lane = tid & 63;
  const int quad = lane >> 4;
  const int l16  = lane & 15;
  const int wave = tid >> 6;
  const int wm   = (wave & 1) * 64;
  const int wn   = (wave >> 1) * 64;

  // staging: 512 16B segments per tile; thread t does segments t and t+256.
  const int segA = tid;
  const int segB = tid + 256;
  const int rA0 = segA >> 2, kA0 = ((segA ^ rA0) & 3) * 8;
  const int rA1 = segB >> 2, kA1 = ((segB ^ rA1) & 3) * 8;

  const f16* Ab = A  + rowBase * (long)K;
  const f16* Bb = Wt + (long)colBase * K;
  const f16* gA0 = Ab + (long)rA0 * K + kA0;
  const f16* gA1 = Ab + (long)rA1 * K + kA1;
  const f16* gB0 = Bb + (long)rA0 * K + kA0;
  const f16* gB1 = Bb + (long)rA1 * K + kA1;

  f32x4 acc[4][4];
  const f32x4 z = {0.f, 0.f, 0.f, 0.f};
#pragma unroll
  for (int i = 0; i < 4; i++)
#pragma unroll
    for (int j = 0; j < 4; j++) acc[i][j] = z;

  // fragment read k-offset after swizzle: (quad ^ (row&3))*8, row&3 == l16&3
  const int qk = (quad ^ (l16 & 3)) * 8;

  for (int k0 = 0; k0 < K; k0 += 32) {
    gload_lds16(gA0 + k0, &lA[segA * 8]);
    gload_lds16(gA1 + k0, &lA[segB * 8]);
    gload_lds16(gB0 + k0, &lB[segA * 8]);
    gload_lds16(gB1 + k0, &lB[segB * 8]);
    __syncthreads();

    f16x8 af[4], bf[4];
#pragma unroll
    for (int mt = 0; mt < 4; mt++)
      af[mt] = *(const f16x8*)&lA[(wm + mt * 16 + l16) * 32 + qk];
#pragma unroll
    for (int nt = 0; nt < 4; nt++)
      bf[nt] = *(const f16x8*)&lB[(wn + nt * 16 + l16) * 32 + qk];

#pragma unroll
    for (int mt = 0; mt < 4; mt++)
#pragma unroll
      for (int nt = 0; nt < 4; nt++)
        acc[mt][nt] = __builtin_amdgcn_mfma_f32_16x16x32_f16(af[mt], bf[nt], acc[mt][nt], 0, 0, 0);
    __syncthreads();
  }

  // epilogue. C/D layout: col=lane&15, row=quad*4+reg (m89-verified)
  if (mode == MODE_ACT) {
    // vectorized: per-wave 16x64 f16 slab in LDS (stride 72 f16 = 9x16B), then
    // 16-B lane-contiguous global stores. Slabs reuse sbuf (post-loop barrier done).
    f16* slab = sbuf + wave * 1152;  // 2304 B per wave
#pragma unroll
    for (int mt = 0; mt < 4; mt++) {
#pragma unroll
      for (int nt = 0; nt < 4; nt++) {
#pragma unroll
        for (int r = 0; r < 4; r++) {
          const int gcol = colBase + wn + nt * 16 + l16;
          float v = acc[mt][nt][r] + bias[gcol];
          if (relu) v = v > 0.f ? v : 0.f;
          slab[(quad * 4 + r) * 72 + nt * 16 + l16] = (f16)v;
        }
      }
      // same-wave LDS dependency: compiler inserts lgkmcnt waits (aliasing)
#pragma unroll
      for (int p = 0; p < 2; p++) {
        const int srow = p * 8 + (lane >> 3);
        const int cc   = lane & 7;
        f16x8 val = *(const f16x8*)&slab[srow * 72 + cc * 8];
        const long grow = rowBase + wm + mt * 16 + srow;
        *(f16x8*)&outAct[grow * 512 + colBase + wn + cc * 8] = val;
      }
    }
  } else {
#pragma unroll
    for (int mt = 0; mt < 4; mt++) {
#pragma unroll
      for (int nt = 0; nt < 4; nt++) {
#pragma unroll
        for (int r = 0; r < 4; r++) {
          const int  mloc = wm + mt * 16 + quad * 4 + r;
          const int  nloc = wn + nt * 16 + l16;
          const long grow = rowBase + mloc;
          const int  gcol = colBase + nloc;
          float v = acc[mt][nt][r];
          if (gcol < realN) v += bias[gcol];
          if (relu) v = v > 0.f ? v : 0.f;
          if (mode == MODE_TREE) {
            if (gcol < OUT_DIM) {
              const long gr   = (long)rowOffset + grow;
              const long bb   = gr >> lvl;
              const long ii   = gr & ((1L << lvl) - 1);
              const long node = nodeBase + ii;
              tree[(bb * N_NODE + node) * TREE_STRIDE + gcol] = (f16)v;
            }
          } else { // MODE_ROOT
            if (gcol == 0) dOut[(long)rowOffset + grow] = v;
          }
        }
      }
    }
  }
}

// ---------------- weight transpose + cast: Wt[n*Kpad + k] = W[k*N + n] ----------------
__global__ void wcast(const float* __restrict__ W, f16* __restrict__ Wt,
                      int K, int N, int Kpad, int Npad) {
  int idx = blockIdx.x * 256 + threadIdx.x;
  if (idx >= Npad * Kpad) return;
  int n = idx / Kpad;
  int k = idx - n * Kpad;
  float v = (n < N && k < K) ? W[(long)k * N + n] : 0.f;
  Wt[idx] = (f16)v;
}

// ---------------- fp32 -> fp16 contiguous cast (4 elems/thread) ----------------
__global__ void cast_chunk(const float* __restrict__ src, f16* __restrict__ dst, long n) {
  long i = ((long)blockIdx.x * 256 + threadIdx.x) * 4;
  if (i >= n) return;
  float4 v = *(const float4*)(src + i);
  f16x4v o = {(f16)v.x, (f16)v.y, (f16)v.z, (f16)v.w};
  *(f16x4v*)(dst + i) = o;
}

// ---------------- gather internal-node inputs: X[r][0:224] = [feat(64)|L(65)|R(65)|0pad] ----------------
__global__ void gather_int(const float* __restrict__ feats, const f16* __restrict__ tree,
                           f16* __restrict__ X, int lvl, int nodeBase, int rowOffset) {
  int c = threadIdx.x;
  if (c >= IIN_PAD) return;
  long r = (long)rowOffset + blockIdx.x;
  int b = (int)(r >> lvl);
  int i = (int)(r & ((1 << lvl) - 1));
  int node = nodeBase + i;
  float v = 0.f;
  if (c < F_DIM) {
    v = feats[((long)b * N_INT + node) * F_DIM + c];
  } else if (c < F_DIM + OUT_DIM) {
    v = (float)tree[((long)b * N_NODE + (2 * node + 1)) * TREE_STRIDE + (c - F_DIM)];
  } else if (c < F_DIM + 2 * OUT_DIM) {
    v = (float)tree[((long)b * N_NODE + (2 * node + 2)) * TREE_STRIDE + (c - F_DIM - OUT_DIM)];
  }
  X[(long)blockIdx.x * IIN_PAD + c] = (f16)v;
}

// ---------------- host orchestration ----------------
extern "C" void kernel_launch(void* const* d_in, const int* in_sizes, int n_in,
                              void* d_out, int out_size, void* d_ws, size_t ws_size,
                              hipStream_t stream) {
  const float* leaf_feats     = (const float*)d_in[0];
  const float* internal_feats = (const float*)d_in[1];
  const float* lw0 = (const float*)d_in[2];
  const float* lb0 = (const float*)d_in[3];
  const float* lw1 = (const float*)d_in[4];
  const float* lb1 = (const float*)d_in[5];
  const float* lw2 = (const float*)d_in[6];
  const float* lb2 = (const float*)d_in[7];
  const float* lwo = (const float*)d_in[8];
  const float* lbo = (const float*)d_in[9];
  const float* iw0 = (const float*)d_in[10];
  const float* ib0 = (const float*)d_in[11];
  const float* iw1 = (const float*)d_in[12];
  const float* ib1 = (const float*)d_in[13];
  const float* iw2 = (const float*)d_in[14];
  const float* ib2 = (const float*)d_in[15];
  const float* iwo = (const float*)d_in[16];
  const float* ibo = (const float*)d_in[17];
  float* dOut = (float*)d_out;

  char* ws = (char*)d_ws;
  size_t off = 0;
  auto alloc = [&](size_t bytes) -> void* {
    void* p = ws + off;
    off += (bytes + 255) & ~(size_t)255;
    return p;
  };

  // fixed regions (~37 MB)
  f16* lw0t = (f16*)alloc((size_t)512 * 64 * 2);
  f16* lw1t = (f16*)alloc((size_t)512 * 512 * 2);
  f16* lw2t = (f16*)alloc((size_t)512 * 512 * 2);
  f16* lwot = (f16*)alloc((size_t)128 * 512 * 2);
  f16* iw0t = (f16*)alloc((size_t)512 * IIN_PAD * 2);
  f16* iw1t = (f16*)alloc((size_t)512 * 512 * 2);
  f16* iw2t = (f16*)alloc((size_t)512 * 512 * 2);
  f16* iwot = (f16*)alloc((size_t)128 * 512 * 2);
  f16* tree = (f16*)alloc((size_t)N_B * N_NODE * TREE_STRIDE * 2);

  // chunked activation regions sized from remaining workspace
  const size_t perRow = (size_t)(F_DIM + IIN_PAD + 512 + 512) * 2;  // 2624 B/row
  long chunk = 0;
  if (ws_size > off + 1024) chunk = (long)((ws_size - off - 1024) / perRow);
  chunk &= ~127L;
  if (chunk > 131072) chunk = 131072;
  if (chunk < 128)    chunk = 128;
  f16* Xleaf = (f16*)alloc((size_t)chunk * F_DIM * 2);
  f16* Xint  = (f16*)alloc((size_t)chunk * IIN_PAD * 2);
  f16* actA  = (f16*)alloc((size_t)chunk * 512 * 2);
  f16* actB  = (f16*)alloc((size_t)chunk * 512 * 2);

  auto wc = [&](const float* W, f16* Wt, int K, int N, int Kpad, int Npad) {
    int total = Npad * Kpad;
    wcast<<<dim3((total + 255) / 256), dim3(256), 0, stream>>>(W, Wt, K, N, Kpad, Npad);
  };
  auto gemm = [&](const f16* Aa, int K, const f16* Wt, const float* bias, int realN,
                  int Npad, long M, int relu, int mode, f16* outAct,
                  int lvl, int nodeBase, long rowOff) {
    int nCB = Npad / 128;
    gemm_f16_k<<<dim3((unsigned)((M / 128) * nCB)), dim3(256), 0, stream>>>(
        Aa, K, Wt, bias, realN, nCB, relu, mode, outAct, tree, lvl, nodeBase, (int)rowOff, dOut);
  };

  // weights: cast + transpose (+pad K to x32, N to x128)
  wc(lw0, lw0t, 64, 512, 64, 512);
  wc(lw1, lw1t, 512, 512, 512, 512);
  wc(lw2, lw2t, 512, 512, 512, 512);
  wc(lwo, lwot, 512, 65, 512, 128);
  wc(iw0, iw0t, 194, 512, IIN_PAD, 512);
  wc(iw1, iw1t, 512, 512, 512, 512);
  wc(iw2, iw2t, 512, 512, 512, 512);
  wc(iwo, iwot, 512, 65, 512, 128);

  // ---- leaf MLP: nodes 511..1022 ----
  const long Mleaf = (long)N_B * N_LEAF;  // 131072
  for (long c0 = 0; c0 < Mleaf; c0 += chunk) {
    long cm = (Mleaf - c0 < chunk) ? (Mleaf - c0) : chunk;
    long n = cm * F_DIM;
    cast_chunk<<<dim3((unsigned)(n / 1024)), dim3(256), 0, stream>>>(leaf_feats + c0 * F_DIM, Xleaf, n);
    gemm(Xleaf, 64,  lw0t, lb0, 512, 512, cm, 1, MODE_ACT, actA, 0, 0, 0);
    gemm(actA, 512,  lw1t, lb1, 512, 512, cm, 1, MODE_ACT, actB, 0, 0, 0);
    gemm(actB, 512,  lw2t, lb2, 512, 512, cm, 1, MODE_ACT, actA, 0, 0, 0);
    gemm(actA, 512,  lwot, lbo, 65,  128, cm, 0, MODE_TREE, nullptr, 9, N_INT, c0);
  }

  // ---- internal levels, bottom-up ----
  for (int l = 8; l >= 0; l--) {
    long R = (long)N_B << l;
    int s = (1 << l) - 1;
    for (long c0 = 0; c0 < R; c0 += chunk) {
      long cm = (R - c0 < chunk) ? (R - c0) : chunk;
      gather_int<<<dim3((unsigned)cm), dim3(256), 0, stream>>>(internal_feats, tree, Xint, l, s, (int)c0);
      gemm(Xint, IIN_PAD, iw0t, ib0, 512, 512, cm, 1, MODE_ACT, actA, 0, 0, 0);
      gemm(actA, 512,     iw1t, ib1, 512, 512, cm, 1, MODE_ACT, actB, 0, 0, 0);
      gemm(actB, 512,     iw2t, ib2, 512, 512, cm, 1, MODE_ACT, actA, 0, 0, 0);
      gemm(actA, 512,     iwot, ibo, 65,  128, cm, 0, (l == 0) ? MODE_ROOT : MODE_TREE, nullptr, l, s, c0);
    }
  }
  (void)in_sizes; (void)n_in; (void)out_size;
}